// Round 1
// baseline (111.091 us; speedup 1.0000x reference)
//
#include <hip/hip_runtime.h>
#include <stdint.h>

#define NPAT 4096
#define DIM  256
#define EPSV 1e-8f
#define BT   128        // block tile (M and N); wave tile 64x64 (2x2 of 32x32x64 MX)
#define NT   (NPAT / BT)            // 32 tiles per dim
#define NBLK (NT * (NT + 1) / 2)    // 528 upper-triangle blocks
#define NSTEP 16        // K = 1024 fp8 bytes = 16 steps of 64
#define NBINS 4096

typedef float f32x4  __attribute__((ext_vector_type(4)));
typedef float f32x16 __attribute__((ext_vector_type(16)));
typedef int   i32x4  __attribute__((ext_vector_type(4)));
typedef int   i32x8  __attribute__((ext_vector_type(8)));

// ---- workspace layout (bytes) ----
// [0..256): scalars: f[0]=sim_sum, f[1]=cox n/d, u[2]=ticket
#define WS_DVAL_OFF 256                          // float4[NPAT]
#define WS_MVEC_OFF (WS_DVAL_OFF + 16*NPAT)      // float4[NPAT]
#define WS_XN_OFF   (WS_MVEC_OFF + 16*NPAT)      // fragment-ready blobs, 4 MB
// XnF chunk layout: per (g = patient>>5, s = K-step) a 2048 B chunk at
//   (g*16 + s)*2048, internally [q:2][l:64][16 B] where l = k_half*32 + (patient&31)
//   and q = (k_in_half >= 16). Linear global_load_lds(16B) staging reproduces this
//   in LDS; fragment reads are stride-16 ds_read_b128 (conflict-free).

__device__ __forceinline__ float decode_margin(const int* pm) {
  int v = *pm;
  if (v > -16777216 && v < 16777216) return (float)v;  // stored as int
  return __int_as_float(v);                            // stored as float bits
}

__device__ __forceinline__ i32x8 ld_op(const uint8_t* p) {
  // 32 B fragment = two b128 reads 1 KB apart (q=0 -> regs 0..3, q=1 -> regs 4..7)
  union { i32x8 w; i32x4 h[2]; } u;
  u.h[0] = *(const i32x4*)(p);
  u.h[1] = *(const i32x4*)(p + 1024);
  return u.w;
}

// ---------- prep: normalize, quantize fp8, scatter into fragment-ready blobs ----------
__global__ __launch_bounds__(256) void prep_kernel(
    const float4* __restrict__ eb0, const float4* __restrict__ eb1,
    const float4* __restrict__ eb2, const float4* __restrict__ eb3,
    uint8_t* __restrict__ XnF, float* __restrict__ dval_f,
    float* __restrict__ mvec_f, float* __restrict__ scal)
{
  const int i    = blockIdx.x;
  const int wv   = threadIdx.x >> 6;   // modality
  const int lane = threadIdx.x & 63;
  const float4* ebs[4] = {eb0, eb1, eb2, eb3};
  const float4 v = ebs[wv][i * (DIM / 4) + lane];
  float s = v.x * v.x + v.y * v.y + v.z * v.z + v.w * v.w;
#pragma unroll
  for (int o = 32; o; o >>= 1) s += __shfl_down(s, o, 64);
  s = __shfl(s, 0, 64);
  const float x0 = __shfl(v.x, 0, 64);
  const bool eq = (v.x == x0) && (v.y == x0) && (v.z == x0) && (v.w == x0);
  const bool miss = (__ballot(eq) == ~0ull);
  const float nrm = sqrtf(s);
  const float den = fmaxf(nrm, EPSV);
  const float inv = miss ? 0.0f : (1.0f / den);
  int p = 0;
  p = __builtin_amdgcn_cvt_pk_fp8_f32(v.x * inv, v.y * inv, p, false);
  p = __builtin_amdgcn_cvt_pk_fp8_f32(v.z * inv, v.w * inv, p, true);
  // fragment-ready scatter into [q][l][16B] chunk layout
  const int g  = i >> 5, r = i & 31;
  const int ss = wv * 4 + (lane >> 4);      // K-step
  const int h  = (lane >> 3) & 1;           // k half (32)
  const int q  = (lane >> 2) & 1;           // 16B half within the 32B fragment
  const int b16 = (lane & 3) * 4;           // byte within 16B
  *(int*)&XnF[(size_t)(g * 16 + ss) * 2048 + q * 1024 +
              (size_t)(h * 32 + r) * 16 + b16] = p;
  if (lane == 0) {
    const float diag = (nrm * nrm) / (den * den);
    dval_f[i * 4 + wv] = miss ? 0.0f : diag;
    mvec_f[i * 4 + wv] = miss ? 0.0f : 1.0f;
  }
  if (i == 0 && threadIdx.x == 0) {
    scal[0] = 0.0f;                    // sim accumulator
    scal[1] = 0.0f;                    // cox n/d
    ((unsigned*)scal)[2] = 0u;         // ticket
  }
}

// ---------- fused: cox (block 0) + sim GEMM (blocks 1..NBLK) + finalize ----------
__global__ __launch_bounds__(256, 3) void sim_gemm_kernel(
    const uint8_t* __restrict__ XnF, const float4* __restrict__ dval,
    const float4* __restrict__ mvec, const int* __restrict__ pmargin,
    const float* __restrict__ h, const int* __restrict__ t,
    const int* __restrict__ e, float* __restrict__ scal,
    float* __restrict__ out)
{
  // 2 x 16 KB double-buffered operand stage; cox and epilogue reuse the same LDS
  __shared__ __align__(16) uint8_t smem[32768 + 256];
  const int L   = blockIdx.x;
  const int tid = threadIdx.x;
  const int lane = tid & 63, wvv = tid >> 6;

  if (L == 0) {
    // ================= Cox path (256 threads) =================
    float* bins = (float*)smem;                      // 16 KB
    float* wt   = (float*)(smem + 16384);            // 4 floats
    float* rn   = (float*)(smem + 16384 + 32);
    float* rd   = (float*)(smem + 16384 + 64);
#pragma unroll
    for (int k = 0; k < 16; ++k) bins[tid + k * 256] = 0.0f;
    __syncthreads();
#pragma unroll
    for (int k = 0; k < 16; ++k) {
      const int i = tid + k * 256;
      atomicAdd(&bins[t[i]], expf(h[i]));
    }
    __syncthreads();
    // suffix scan: bins[b] <- sum_{v>=b} bins[v]; thread owns bins[16t..16t+15]
    float seg[16]; float part = 0.0f;
#pragma unroll
    for (int k = 0; k < 16; ++k) { seg[k] = bins[tid * 16 + k]; part += seg[k]; }
    float sfx = part;                                // inclusive suffix within wave
#pragma unroll
    for (int off = 1; off < 64; off <<= 1) {
      const float u = __shfl_down(sfx, off, 64);
      if (lane + off < 64) sfx += u;
    }
    if (lane == 0) wt[wvv] = sfx;                    // wave totals
    __syncthreads();
    float above = 0.0f;
    for (int w = wvv + 1; w < 4; ++w) above += wt[w];
    float run = above + (sfx - part);                // strictly-after my segment
#pragma unroll
    for (int k = 15; k >= 0; --k) { run += seg[k]; bins[tid * 16 + k] = run; }
    __syncthreads();
    float nloc = 0.0f, dloc = 0.0f;
#pragma unroll
    for (int k = 0; k < 16; ++k) {
      const int i = tid + k * 256;
      const float ei = (float)e[i];
      if (ei != 0.0f) { nloc += ei * (h[i] - logf(bins[t[i]])); dloc += ei; }
    }
#pragma unroll
    for (int o = 32; o; o >>= 1) {
      nloc += __shfl_down(nloc, o, 64);
      dloc += __shfl_down(dloc, o, 64);
    }
    if (lane == 0) { rn[wvv] = nloc; rd[wvv] = dloc; }
    __syncthreads();
    if (tid == 0) {
      float n = 0.0f, d = 0.0f;
#pragma unroll
      for (int k = 0; k < 4; ++k) { n += rn[k]; d += rd[k]; }
      atomicExch(&scal[1], n / d);                   // publish cox
      __threadfence();
      const unsigned old = atomicAdd(&((unsigned*)scal)[2], 1u);
      if (old == NBLK) {                             // last of NBLK+1 blocks
        __threadfence();
        out[0] = atomicAdd(&scal[0], 0.0f) - (n / d);
      }
    }
    return;
  }

  // ================= GEMM path =================
  const int T = L - 1;
  int bi = (int)((2 * NT + 1 - sqrtf((float)((2 * NT + 1) * (2 * NT + 1)) - 8.0f * T)) * 0.5f);
  if (bi < 0) bi = 0;
  if (bi > NT - 1) bi = NT - 1;
  while (bi > 0 && bi * NT - bi * (bi - 1) / 2 > T) --bi;
  while ((bi + 1) * NT - (bi + 1) * bi / 2 <= T) ++bi;
  const int bj = bi + (T - (bi * NT - bi * (bi - 1) / 2));

  const int wi = wvv >> 1, wj = wvv & 1;        // wave tile 64x64 within 128x128
  const bool isDiag = (bi == bj);

  // Stage one K-step (16 KB = A: groups bi*4..+3, B: groups bj*4..+3) into LDS.
  // 16 chunk-halves of 1 KB; wave wvv issues ii = wvv*4 .. wvv*4+3.
  // Diag blocks: B == A, stage only ii<8 (waves 2,3 idle) and alias B reads to A.
#define STAGE(BUFOFF, S) do {                                                        \
    if (!isDiag || wvv < 2) {                                                        \
      _Pragma("unroll")                                                              \
      for (int t_ = 0; t_ < 4; ++t_) {                                               \
        const int ii = wvv * 4 + t_;                                                 \
        const int grp = (ii < 8) ? (bi * 4 + (ii >> 1)) : (bj * 4 + ((ii >> 1) & 3));\
        const uint8_t* src = XnF + (size_t)(grp * 16 + (S)) * 2048                   \
                             + (ii & 1) * 1024 + lane * 16;                          \
        uint8_t* dst = (uint8_t*)smem + (BUFOFF) + ii * 1024;                        \
        __builtin_amdgcn_global_load_lds(                                            \
            (const __attribute__((address_space(1))) unsigned int*)src,              \
            (__attribute__((address_space(3))) unsigned int*)dst, 16, 0, 0);         \
      }                                                                              \
    }                                                                                \
  } while (0)

  f32x16 acc[2][2] = {};

  STAGE(0, 0);
  int cur = 0;
#pragma unroll 1
  for (int s = 0; s < NSTEP; ++s) {
    if (s + 1 < NSTEP) STAGE((cur ^ 1) * 16384, s + 1);
    __syncthreads();                              // buf[cur] staged (vmcnt drain)
    const uint8_t* aB = (const uint8_t*)smem + cur * 16384 + (size_t)lane * 16;
    const uint8_t* bB = aB + (isDiag ? 0 : 8192);
    const i32x8 a0 = ld_op(aB + (wi * 2 + 0) * 2048);
    const i32x8 a1 = ld_op(aB + (wi * 2 + 1) * 2048);
    const i32x8 b0 = ld_op(bB + (wj * 2 + 0) * 2048);
    const i32x8 b1 = ld_op(bB + (wj * 2 + 1) * 2048);
    acc[0][0] = __builtin_amdgcn_mfma_scale_f32_32x32x64_f8f6f4(
        a0, b0, acc[0][0], 0, 0, 0, 0x7F7F7F7F, 0, 0x7F7F7F7F);
    acc[0][1] = __builtin_amdgcn_mfma_scale_f32_32x32x64_f8f6f4(
        a0, b1, acc[0][1], 0, 0, 0, 0x7F7F7F7F, 0, 0x7F7F7F7F);
    acc[1][0] = __builtin_amdgcn_mfma_scale_f32_32x32x64_f8f6f4(
        a1, b0, acc[1][0], 0, 0, 0, 0x7F7F7F7F, 0, 0x7F7F7F7F);
    acc[1][1] = __builtin_amdgcn_mfma_scale_f32_32x32x64_f8f6f4(
        a1, b1, acc[1][1], 0, 0, 0, 0x7F7F7F7F, 0, 0x7F7F7F7F);
    __syncthreads();                              // all reads of buf[cur] done
    cur ^= 1;
  }
#undef STAGE

  // epilogue: stage dval/mvec for both tiles in LDS (8 KB, reuses stage buffer)
  float4* eRDi = (float4*)smem;
  float4* eCMi = (float4*)smem + BT;
  float4* eRDj = (float4*)smem + 2 * BT;
  float4* eCMj = (float4*)smem + 3 * BT;
  float*  wred = (float*)(smem + 8192);
  if (tid < BT) {
    eRDi[tid] = dval[bi * BT + tid];
    eCMi[tid] = mvec[bi * BT + tid];
  } else {
    const int ss = tid - BT;
    eRDj[ss] = dval[bj * BT + ss];
    eCMj[ss] = mvec[bj * BT + ss];
  }
  __syncthreads();

  const float margin = decode_margin(pmargin);
  float local = 0.0f;
  const int colA = lane & 31, hsel = lane >> 5;  // C/D: col=lane&31, row=(reg&3)+8*(reg>>2)+4*(lane>>5)
#pragma unroll
  for (int mi = 0; mi < 2; ++mi) {
#pragma unroll
    for (int mj = 0; mj < 2; ++mj) {
      const int jl = wj * 64 + mj * 32 + colA;
      const float4 cmj = eCMj[jl];
      const float4 rdj = eRDj[jl];
#pragma unroll
      for (int rr = 0; rr < 16; ++rr) {
        const int il = wi * 64 + mi * 32 + (rr & 3) + 8 * (rr >> 2) + 4 * hsel;
        const float4 rdi = eRDi[il];
        const float sv = acc[mi][mj][rr];
        const float own_ij = rdi.x * cmj.x + rdi.y * cmj.y + rdi.z * cmj.z + rdi.w * cmj.w;
        const float v1 = fmaxf(margin - sv + own_ij, 0.0f);
        local += (isDiag && il == jl) ? 0.0f : v1;
        if (!isDiag) {                          // transposed pair (j,i)
          const float4 cmi = eCMi[il];
          const float own_ji = rdj.x * cmi.x + rdj.y * cmi.y + rdj.z * cmi.z + rdj.w * cmi.w;
          local += fmaxf(margin - sv + own_ji, 0.0f);
        }
      }
    }
  }
#pragma unroll
  for (int o = 32; o; o >>= 1) local += __shfl_down(local, o, 64);
  if (lane == 0) wred[wvv] = local;
  __syncthreads();
  if (tid == 0) {
    atomicAdd(&scal[0], wred[0] + wred[1] + wred[2] + wred[3]);
    __threadfence();
    const unsigned old = atomicAdd(&((unsigned*)scal)[2], 1u);
    if (old == NBLK) {                          // last of NBLK+1 blocks
      __threadfence();
      out[0] = atomicAdd(&scal[0], 0.0f) - atomicAdd(&scal[1], 0.0f);
    }
  }
}

extern "C" void kernel_launch(void* const* d_in, const int* in_sizes, int n_in,
                              void* d_out, int out_size, void* d_ws, size_t ws_size,
                              hipStream_t stream) {
  const float* h    = (const float*)d_in[0];
  const int*   t    = (const int*)  d_in[1];
  const int*   e    = (const int*)  d_in[2];
  const float4* eb0 = (const float4*)d_in[3];
  const float4* eb1 = (const float4*)d_in[4];
  const float4* eb2 = (const float4*)d_in[5];
  const float4* eb3 = (const float4*)d_in[6];
  const int*   pm   = (const int*)  d_in[7];

  char*    ws   = (char*)d_ws;
  float*   scal = (float*)ws;
  float*   dvf  = (float*)(ws + WS_DVAL_OFF);
  float*   mvf  = (float*)(ws + WS_MVEC_OFF);
  uint8_t* XnF  = (uint8_t*)(ws + WS_XN_OFF);

  prep_kernel<<<NPAT, 256, 0, stream>>>(eb0, eb1, eb2, eb3, XnF, dvf, mvf, scal);
  sim_gemm_kernel<<<NBLK + 1, 256, 0, stream>>>(XnF, (const float4*)dvf, (const float4*)mvf,
                                                pm, h, t, e, scal, (float*)d_out);
}